// Round 1
// baseline (830.556 us; speedup 1.0000x reference)
//
#include <hip/hip_runtime.h>

// Problem constants (fixed by reference)
#define NATOMS 200000
#define NEDGE  800000
#define NBOND  400000   // NEDGE/2
#define HDIM   512
#define AF     133
#define BFEAT  14
#define NGRAPH 4096

// d_out layout: node_pred [NATOMS*AF] | edge_pred [NBOND*BFEAT] | graph_pred [NGRAPH]
#define NODE_OUT_SZ (NATOMS * AF)          // 26,600,000
#define EDGE_OUT_SZ (NBOND * BFEAT)        //  5,600,000

// ws layout (bytes)
#define WS_P     0                          // float  [NATOMS][16]  (cols 0..13 used)  12,800,000 B
#define WS_BMAT  12800000                   // f16    [160][512]    163,840 B  (n-major, transposed)
#define WS_BIAS  12963840                   // float  [160]         640 B
#define WS_GE    12964480                   // f16    [4096][512]   4,194,304 B
#define WS_WG1T  17158784                   // f16    [512][512]    524,288 B (n-major)

typedef _Float16 half8 __attribute__((ext_vector_type(8)));
typedef float floatx4 __attribute__((ext_vector_type(4)));

// ---------------------------------------------------------------------------
// Pack: combined B matrix [W_node | W_edge] transposed to n-major f16, bias,
// W_g1 transposed f16, graph_pred init to b_g2.
// ---------------------------------------------------------------------------
__global__ void pack_kernel(const float* __restrict__ Wn, const float* __restrict__ bn,
                            const float* __restrict__ We, const float* __restrict__ be,
                            const float* __restrict__ Wg1, const float* __restrict__ bg2,
                            _Float16* __restrict__ Bmat, float* __restrict__ bias,
                            _Float16* __restrict__ Wg1t, float* __restrict__ gpred) {
    int idx = blockIdx.x * 256 + threadIdx.x;
    if (idx < 160 * 512) {                      // Bmat[n][k] = W[k][n]
        int n = idx >> 9, k = idx & 511;
        float v = 0.f;
        if (n < AF)              v = Wn[k * AF + n];
        else if (n < AF + BFEAT) v = We[k * BFEAT + (n - AF)];
        Bmat[idx] = (_Float16)v;
    } else if (idx < 160 * 512 + 512 * 512) {   // Wg1t[n][k] = Wg1[k][n]
        int i = idx - 160 * 512;
        int n = i >> 9, k = i & 511;
        Wg1t[i] = (_Float16)Wg1[k * HDIM + n];
    } else if (idx < 160 * 512 + 512 * 512 + 160) {
        int n = idx - (160 * 512 + 512 * 512);
        float v = 0.f;
        if (n < AF)              v = bn[n];
        else if (n < AF + BFEAT) v = be[n - AF];
        bias[n] = v;
    } else if (idx < 160 * 512 + 512 * 512 + 160 + NGRAPH) {
        gpred[idx - (160 * 512 + 512 * 512 + 160)] = bg2[0];
    }
}

// ---------------------------------------------------------------------------
// Pooling: batch is sorted -> one block per graph, binary search the segment,
// sum rows (fp32 accumulate), store f16 graph embedding. No atomics.
// ---------------------------------------------------------------------------
__global__ __launch_bounds__(256) void pool_kernel(const float* __restrict__ A,
                                                   const int* __restrict__ batch,
                                                   _Float16* __restrict__ GE) {
    int g = blockIdx.x;
    int t = threadIdx.x;
    int lo = 0, hi = NATOMS;
    while (lo < hi) { int mid = (lo + hi) >> 1; if (batch[mid] < g) lo = mid + 1; else hi = mid; }
    int start = lo;
    hi = NATOMS;
    while (lo < hi) { int mid = (lo + hi) >> 1; if (batch[mid] < g + 1) lo = mid + 1; else hi = mid; }
    int end = lo;
    float s0 = 0.f, s1 = 0.f;
    for (int i = start; i < end; ++i) {
        s0 += A[(size_t)i * HDIM + t];
        s1 += A[(size_t)i * HDIM + t + 256];
    }
    GE[(size_t)g * HDIM + t]       = (_Float16)s0;
    GE[(size_t)g * HDIM + t + 256] = (_Float16)s1;
}

// ---------------------------------------------------------------------------
// GEMM1: C[N x 160] = A(f32->f16)[N x 512] @ Bmat^T, cols 0..132 -> node_pred,
// cols 133..146 -> P (stride 16). BM=128 BN=160 BK=64, 4 waves (2x2), wave
// tile 64x80 = 4x5 MFMA 16x16x32 f16 tiles.
// ---------------------------------------------------------------------------
__global__ __launch_bounds__(256) void gemm_node(const float* __restrict__ A,
                                                 const _Float16* __restrict__ Bm,
                                                 const float* __restrict__ bias,
                                                 float* __restrict__ node_out,
                                                 float* __restrict__ P) {
    __shared__ _Float16 As[128][72];   // +8 pad: 2-way-max bank aliasing
    __shared__ _Float16 Bs[160][72];

    const int t    = threadIdx.x;
    const int bm   = blockIdx.x;
    const int w    = t >> 6, l = t & 63, quad = l >> 4, lr = l & 15;
    const int wm   = w & 1, wn = w >> 1;

    floatx4 acc[4][5];
    for (int mt = 0; mt < 4; ++mt)
        for (int nt = 0; nt < 5; ++nt)
            acc[mt][nt] = (floatx4){0.f, 0.f, 0.f, 0.f};

    const int arow0 = t >> 2;          // 0..63
    const int aseg  = (t & 3) * 16;    // 0,16,32,48

    for (int ko = 0; ko < 8; ++ko) {
        const int k0 = ko * 64;
        // ---- global loads into regs
        float4 av[2][4];
        for (int p = 0; p < 2; ++p) {
            int row = arow0 + p * 64;
            long grow = (long)bm * 128 + row;
            if (grow < NATOMS) {
                const float4* src = (const float4*)(A + grow * HDIM + k0 + aseg);
                av[p][0] = src[0]; av[p][1] = src[1]; av[p][2] = src[2]; av[p][3] = src[3];
            } else {
                av[p][0] = av[p][1] = av[p][2] = av[p][3] = make_float4(0.f, 0.f, 0.f, 0.f);
            }
        }
        uint4 bv[5];
        for (int it = 0; it < 5; ++it) {
            int idx = t + it * 256;            // < 1280
            int row = idx >> 3, c = (idx & 7) * 8;
            bv[it] = *(const uint4*)(Bm + row * HDIM + k0 + c);
        }
        __syncthreads();
        // ---- LDS writes (fp32 -> f16 cast for A)
        for (int p = 0; p < 2; ++p) {
            int row = arow0 + p * 64;
            half8 h0 = {(_Float16)av[p][0].x, (_Float16)av[p][0].y, (_Float16)av[p][0].z, (_Float16)av[p][0].w,
                        (_Float16)av[p][1].x, (_Float16)av[p][1].y, (_Float16)av[p][1].z, (_Float16)av[p][1].w};
            half8 h1 = {(_Float16)av[p][2].x, (_Float16)av[p][2].y, (_Float16)av[p][2].z, (_Float16)av[p][2].w,
                        (_Float16)av[p][3].x, (_Float16)av[p][3].y, (_Float16)av[p][3].z, (_Float16)av[p][3].w};
            *(half8*)&As[row][aseg]     = h0;
            *(half8*)&As[row][aseg + 8] = h1;
        }
        for (int it = 0; it < 5; ++it) {
            int idx = t + it * 256;
            int row = idx >> 3, c = (idx & 7) * 8;
            *(uint4*)&Bs[row][c] = bv[it];
        }
        __syncthreads();
        // ---- MFMA
        for (int kk = 0; kk < 64; kk += 32) {
            half8 af[4], bf[5];
            for (int mt = 0; mt < 4; ++mt)
                af[mt] = *(const half8*)&As[wm * 64 + mt * 16 + lr][kk + quad * 8];
            for (int nt = 0; nt < 5; ++nt)
                bf[nt] = *(const half8*)&Bs[wn * 80 + nt * 16 + lr][kk + quad * 8];
            for (int mt = 0; mt < 4; ++mt)
                for (int nt = 0; nt < 5; ++nt)
                    acc[mt][nt] = __builtin_amdgcn_mfma_f32_16x16x32_f16(af[mt], bf[nt], acc[mt][nt], 0, 0, 0);
        }
    }

    // ---- epilogue: +bias, scatter to node_pred / P
    float biasv[5];
    for (int nt = 0; nt < 5; ++nt) biasv[nt] = bias[wn * 80 + nt * 16 + lr];
    for (int mt = 0; mt < 4; ++mt) {
        int rbase = bm * 128 + wm * 64 + mt * 16 + quad * 4;
        for (int r = 0; r < 4; ++r) {
            int grow = rbase + r;
            if (grow >= NATOMS) continue;
            for (int nt = 0; nt < 5; ++nt) {
                int gcol = wn * 80 + nt * 16 + lr;
                float v = acc[mt][nt][r] + biasv[nt];
                if (gcol < AF)                  node_out[(long)grow * AF + gcol] = v;
                else if (gcol < AF + BFEAT)     P[(long)grow * 16 + (gcol - AF)] = v;
            }
        }
    }
}

// ---------------------------------------------------------------------------
// Edge head: keep[k] = 2k (rev[e] = e^1 on pristine input), so
// edge_pred[k] = 0.5*(P[heads[2k]] + P[tails[2k]]). 16 bonds per block.
// ---------------------------------------------------------------------------
__global__ __launch_bounds__(256) void edge_kernel(const int* __restrict__ ei,
                                                   const float* __restrict__ P,
                                                   float* __restrict__ eout) {
    int t  = threadIdx.x;
    int j  = t & 15, bi = t >> 4;
    int b  = blockIdx.x * 16 + bi;
    if (b >= NBOND) return;
    if (j < BFEAT) {
        int e  = 2 * b;
        int a1 = ei[e];
        int a2 = ei[NEDGE + e];
        float v = 0.5f * (P[(size_t)a1 * 16 + j] + P[(size_t)a2 * 16 + j]);
        eout[(size_t)b * BFEAT + j] = v;
    }
}

// ---------------------------------------------------------------------------
// Graph head: relu(GE @ Wg1 + b_g1) @ Wg2 (+b_g2, pre-initialized). GEMM
// 4096x512x512 f16 with fused relu/dot epilogue; partial col-sums reduced
// across the 16 col-lanes, atomicAdd per row per wave-col.
// ---------------------------------------------------------------------------
__global__ __launch_bounds__(256) void gemm_graph(const _Float16* __restrict__ GE,
                                                  const _Float16* __restrict__ Bt,
                                                  const float* __restrict__ bg1,
                                                  const float* __restrict__ wg2,
                                                  float* __restrict__ gpred) {
    __shared__ _Float16 As[128][72];
    __shared__ _Float16 Bs[128][72];

    const int t   = threadIdx.x;
    const int bmb = blockIdx.x, bnb = blockIdx.y;
    const int w   = t >> 6, l = t & 63, quad = l >> 4, lr = l & 15;
    const int wm  = w & 1, wn = w >> 1;

    floatx4 acc[4][4];
    for (int mt = 0; mt < 4; ++mt)
        for (int nt = 0; nt < 4; ++nt)
            acc[mt][nt] = (floatx4){0.f, 0.f, 0.f, 0.f};

    for (int ko = 0; ko < 8; ++ko) {
        const int k0 = ko * 64;
        uint4 avv[4], bvv[4];
        for (int it = 0; it < 4; ++it) {
            int idx = t + it * 256;            // < 1024
            int row = idx >> 3, c = (idx & 7) * 8;
            avv[it] = *(const uint4*)(GE + (size_t)(bmb * 128 + row) * HDIM + k0 + c);
            bvv[it] = *(const uint4*)(Bt + (size_t)(bnb * 128 + row) * HDIM + k0 + c);
        }
        __syncthreads();
        for (int it = 0; it < 4; ++it) {
            int idx = t + it * 256;
            int row = idx >> 3, c = (idx & 7) * 8;
            *(uint4*)&As[row][c] = avv[it];
            *(uint4*)&Bs[row][c] = bvv[it];
        }
        __syncthreads();
        for (int kk = 0; kk < 64; kk += 32) {
            half8 af[4], bf[4];
            for (int mt = 0; mt < 4; ++mt)
                af[mt] = *(const half8*)&As[wm * 64 + mt * 16 + lr][kk + quad * 8];
            for (int nt = 0; nt < 4; ++nt)
                bf[nt] = *(const half8*)&Bs[wn * 64 + nt * 16 + lr][kk + quad * 8];
            for (int mt = 0; mt < 4; ++mt)
                for (int nt = 0; nt < 4; ++nt)
                    acc[mt][nt] = __builtin_amdgcn_mfma_f32_16x16x32_f16(af[mt], bf[nt], acc[mt][nt], 0, 0, 0);
        }
    }

    float bg1v[4], wg2v[4];
    for (int nt = 0; nt < 4; ++nt) {
        int col = bnb * 128 + wn * 64 + nt * 16 + lr;
        bg1v[nt] = bg1[col];
        wg2v[nt] = wg2[col];
    }
    for (int mt = 0; mt < 4; ++mt) {
        for (int r = 0; r < 4; ++r) {
            int row = bmb * 128 + wm * 64 + mt * 16 + quad * 4 + r;
            float partial = 0.f;
            for (int nt = 0; nt < 4; ++nt) {
                float v = acc[mt][nt][r] + bg1v[nt];
                v = v > 0.f ? v : 0.f;
                partial += v * wg2v[nt];
            }
            partial += __shfl_xor(partial, 1);
            partial += __shfl_xor(partial, 2);
            partial += __shfl_xor(partial, 4);
            partial += __shfl_xor(partial, 8);
            if (lr == 0) atomicAdd(&gpred[row], partial);
        }
    }
}

// ---------------------------------------------------------------------------
extern "C" void kernel_launch(void* const* d_in, const int* in_sizes, int n_in,
                              void* d_out, int out_size, void* d_ws, size_t ws_size,
                              hipStream_t stream) {
    const float* A    = (const float*)d_in[0];
    const float* Wn   = (const float*)d_in[1];
    const float* bn   = (const float*)d_in[2];
    const float* We   = (const float*)d_in[3];
    const float* be   = (const float*)d_in[4];
    const float* Wg1  = (const float*)d_in[5];
    const float* bg1  = (const float*)d_in[6];
    const float* Wg2  = (const float*)d_in[7];
    const float* bg2  = (const float*)d_in[8];
    const int*   ei   = (const int*)d_in[9];
    const int*   batch= (const int*)d_in[11];

    char* ws = (char*)d_ws;
    float*    P    = (float*)(ws + WS_P);
    _Float16* Bmat = (_Float16*)(ws + WS_BMAT);
    float*    bias = (float*)(ws + WS_BIAS);
    _Float16* GE   = (_Float16*)(ws + WS_GE);
    _Float16* Wg1t = (_Float16*)(ws + WS_WG1T);

    float* node_out = (float*)d_out;
    float* edge_out = node_out + NODE_OUT_SZ;
    float* gpred    = edge_out + EDGE_OUT_SZ;

    pack_kernel<<<dim3(1361), dim3(256), 0, stream>>>(Wn, bn, We, be, Wg1, bg2, Bmat, bias, Wg1t, gpred);
    pool_kernel<<<dim3(NGRAPH), dim3(256), 0, stream>>>(A, batch, GE);
    gemm_node<<<dim3((NATOMS + 127) / 128), dim3(256), 0, stream>>>(A, Bmat, bias, node_out, P);
    edge_kernel<<<dim3(NBOND / 16), dim3(256), 0, stream>>>(ei, P, edge_out);
    gemm_graph<<<dim3(32, 4), dim3(256), 0, stream>>>(GE, Wg1t, bg1, Wg2, gpred);
}

// Round 2
// 746.449 us; speedup vs baseline: 1.1127x; 1.1127x over previous
//
#include <hip/hip_runtime.h>

// Problem constants (fixed by reference)
#define NATOMS 200000
#define NEDGE  800000
#define NBOND  400000   // NEDGE/2
#define HDIM   512
#define AF     133
#define BFEAT  14
#define NGRAPH 4096

// d_out layout: node_pred [NATOMS*AF] | edge_pred [NBOND*BFEAT] | graph_pred [NGRAPH]
#define NODE_OUT_SZ (NATOMS * AF)          // 26,600,000
#define EDGE_OUT_SZ (NBOND * BFEAT)        //  5,600,000

// ws layout (bytes)
#define WS_P     0                          // float  [NATOMS][16]  (cols 0..13 used)  12,800,000 B
#define WS_BMAT  12800000                   // f16    [160][512]    163,840 B  (n-major, transposed)
#define WS_BIAS  12963840                   // float  [160]         640 B
#define WS_GEF   12964480                   // float  [4096][512]   8,388,608 B (pooled emb, fp32, atomics)
#define WS_WG1T  21353088                   // f16    [512][512]    524,288 B (n-major)

typedef _Float16 half8 __attribute__((ext_vector_type(8)));
typedef float floatx4 __attribute__((ext_vector_type(4)));

// ---------------------------------------------------------------------------
// Pack: combined B matrix [W_node | W_edge] transposed to n-major f16, bias,
// W_g1 transposed f16, graph_pred init to b_g2.
// ---------------------------------------------------------------------------
__global__ void pack_kernel(const float* __restrict__ Wn, const float* __restrict__ bn,
                            const float* __restrict__ We, const float* __restrict__ be,
                            const float* __restrict__ Wg1, const float* __restrict__ bg2,
                            _Float16* __restrict__ Bmat, float* __restrict__ bias,
                            _Float16* __restrict__ Wg1t, float* __restrict__ gpred) {
    int idx = blockIdx.x * 256 + threadIdx.x;
    if (idx < 160 * 512) {                      // Bmat[n][k] = W[k][n]
        int n = idx >> 9, k = idx & 511;
        float v = 0.f;
        if (n < AF)              v = Wn[k * AF + n];
        else if (n < AF + BFEAT) v = We[k * BFEAT + (n - AF)];
        Bmat[idx] = (_Float16)v;
    } else if (idx < 160 * 512 + 512 * 512) {   // Wg1t[n][k] = Wg1[k][n]
        int i = idx - 160 * 512;
        int n = i >> 9, k = i & 511;
        Wg1t[i] = (_Float16)Wg1[k * HDIM + n];
    } else if (idx < 160 * 512 + 512 * 512 + 160) {
        int n = idx - (160 * 512 + 512 * 512);
        float v = 0.f;
        if (n < AF)              v = bn[n];
        else if (n < AF + BFEAT) v = be[n - AF];
        bias[n] = v;
    } else if (idx < 160 * 512 + 512 * 512 + 160 + NGRAPH) {
        gpred[idx - (160 * 512 + 512 * 512 + 160)] = bg2[0];
    }
}

// Zero the fp32 graph-embedding accumulator (ws is poisoned 0xAA).
__global__ void zero_ge(float4* __restrict__ GEf4) {
    GEf4[blockIdx.x * 256 + threadIdx.x] = make_float4(0.f, 0.f, 0.f, 0.f);
}

// ---------------------------------------------------------------------------
// GEMM1: C[N x 160] = A(f32->f16)[N x 512] @ Bmat^T, cols 0..132 -> node_pred,
// cols 133..146 -> P (stride 16). BM=128 BN=160 BK=64, 4 waves (2x2), wave
// tile 64x80 = 4x5 MFMA 16x16x32 f16 tiles.
// FUSED POOLING: while each 128x64 As tile is resident in LDS, wave w sums
// rows w*32..w*32+31 for its 64 columns, segmented by graph id (wave-uniform
// branch: bg[r] broadcasts across the wave's 64 col-lanes), flushing one
// coalesced 256B fp32 atomicAdd burst per graph boundary into GEf.
// ---------------------------------------------------------------------------
__global__ __launch_bounds__(256) void gemm_node(const float* __restrict__ A,
                                                 const _Float16* __restrict__ Bm,
                                                 const float* __restrict__ bias,
                                                 const int* __restrict__ batch,
                                                 float* __restrict__ node_out,
                                                 float* __restrict__ P,
                                                 float* __restrict__ GEf) {
    __shared__ _Float16 As[128][72];   // +8 pad: 2-way-max bank aliasing
    __shared__ _Float16 Bs[160][72];
    __shared__ int bg[128];

    const int t    = threadIdx.x;
    const int bm   = blockIdx.x;
    const int w    = t >> 6, l = t & 63, quad = l >> 4, lr = l & 15;
    const int wm   = w & 1, wn = w >> 1;

    if (t < 128) {
        int grow = bm * 128 + t;
        bg[t] = (grow < NATOMS) ? batch[grow] : -1;
    }

    floatx4 acc[4][5];
    for (int mt = 0; mt < 4; ++mt)
        for (int nt = 0; nt < 5; ++nt)
            acc[mt][nt] = (floatx4){0.f, 0.f, 0.f, 0.f};

    const int arow0 = t >> 2;          // 0..63
    const int aseg  = (t & 3) * 16;    // 0,16,32,48
    const int pc    = t & 63;          // pooling column within the ko tile
    const int pq    = w;               // pooling row-quarter = wave id

    for (int ko = 0; ko < 8; ++ko) {
        const int k0 = ko * 64;
        // ---- global loads into regs
        float4 av[2][4];
        for (int p = 0; p < 2; ++p) {
            int row = arow0 + p * 64;
            long grow = (long)bm * 128 + row;
            if (grow < NATOMS) {
                const float4* src = (const float4*)(A + grow * HDIM + k0 + aseg);
                av[p][0] = src[0]; av[p][1] = src[1]; av[p][2] = src[2]; av[p][3] = src[3];
            } else {
                av[p][0] = av[p][1] = av[p][2] = av[p][3] = make_float4(0.f, 0.f, 0.f, 0.f);
            }
        }
        uint4 bv[5];
        for (int it = 0; it < 5; ++it) {
            int idx = t + it * 256;            // < 1280
            int row = idx >> 3, c = (idx & 7) * 8;
            bv[it] = *(const uint4*)(Bm + row * HDIM + k0 + c);
        }
        __syncthreads();   // protect previous iteration's LDS reads (MFMA + pooling)
        // ---- LDS writes (fp32 -> f16 cast for A)
        for (int p = 0; p < 2; ++p) {
            int row = arow0 + p * 64;
            half8 h0 = {(_Float16)av[p][0].x, (_Float16)av[p][0].y, (_Float16)av[p][0].z, (_Float16)av[p][0].w,
                        (_Float16)av[p][1].x, (_Float16)av[p][1].y, (_Float16)av[p][1].z, (_Float16)av[p][1].w};
            half8 h1 = {(_Float16)av[p][2].x, (_Float16)av[p][2].y, (_Float16)av[p][2].z, (_Float16)av[p][2].w,
                        (_Float16)av[p][3].x, (_Float16)av[p][3].y, (_Float16)av[p][3].z, (_Float16)av[p][3].w};
            *(half8*)&As[row][aseg]     = h0;
            *(half8*)&As[row][aseg + 8] = h1;
        }
        for (int it = 0; it < 5; ++it) {
            int idx = t + it * 256;
            int row = idx >> 3, c = (idx & 7) * 8;
            *(uint4*)&Bs[row][c] = bv[it];
        }
        __syncthreads();
        // ---- MFMA
        for (int kk = 0; kk < 64; kk += 32) {
            half8 af[4], bf[5];
            for (int mt = 0; mt < 4; ++mt)
                af[mt] = *(const half8*)&As[wm * 64 + mt * 16 + lr][kk + quad * 8];
            for (int nt = 0; nt < 5; ++nt)
                bf[nt] = *(const half8*)&Bs[wn * 80 + nt * 16 + lr][kk + quad * 8];
            for (int mt = 0; mt < 4; ++mt)
                for (int nt = 0; nt < 5; ++nt)
                    acc[mt][nt] = __builtin_amdgcn_mfma_f32_16x16x32_f16(af[mt], bf[nt], acc[mt][nt], 0, 0, 0);
        }
        // ---- fused segment-sum pooling over this tile's 64 columns
        {
            float psum = 0.f;
            int pg = bg[pq * 32];
            for (int r = pq * 32; r < pq * 32 + 32; ++r) {
                int gid = bg[r];                       // wave-uniform broadcast
                if (gid != pg) {                       // wave-uniform branch
                    if (pg >= 0) atomicAdd(&GEf[(size_t)pg * HDIM + k0 + pc], psum);
                    psum = 0.f; pg = gid;
                }
                psum += (float)As[r][pc];
            }
            if (pg >= 0) atomicAdd(&GEf[(size_t)pg * HDIM + k0 + pc], psum);
        }
    }

    // ---- epilogue: +bias, scatter to node_pred / P
    float biasv[5];
    for (int nt = 0; nt < 5; ++nt) biasv[nt] = bias[wn * 80 + nt * 16 + lr];
    for (int mt = 0; mt < 4; ++mt) {
        int rbase = bm * 128 + wm * 64 + mt * 16 + quad * 4;
        for (int r = 0; r < 4; ++r) {
            int grow = rbase + r;
            if (grow >= NATOMS) continue;
            for (int nt = 0; nt < 5; ++nt) {
                int gcol = wn * 80 + nt * 16 + lr;
                float v = acc[mt][nt][r] + biasv[nt];
                if (gcol < AF)                  node_out[(long)grow * AF + gcol] = v;
                else if (gcol < AF + BFEAT)     P[(long)grow * 16 + (gcol - AF)] = v;
            }
        }
    }
}

// ---------------------------------------------------------------------------
// Edge head: keep[k] = 2k (rev[e] = e^1 on pristine input), so
// edge_pred[k] = 0.5*(P[heads[2k]] + P[tails[2k]]). 16 bonds per block.
// ---------------------------------------------------------------------------
__global__ __launch_bounds__(256) void edge_kernel(const int* __restrict__ ei,
                                                   const float* __restrict__ P,
                                                   float* __restrict__ eout) {
    int t  = threadIdx.x;
    int j  = t & 15, bi = t >> 4;
    int b  = blockIdx.x * 16 + bi;
    if (b >= NBOND) return;
    if (j < BFEAT) {
        int e  = 2 * b;
        int a1 = ei[e];
        int a2 = ei[NEDGE + e];
        float v = 0.5f * (P[(size_t)a1 * 16 + j] + P[(size_t)a2 * 16 + j]);
        eout[(size_t)b * BFEAT + j] = v;
    }
}

// ---------------------------------------------------------------------------
// Graph head: relu(GE @ Wg1 + b_g1) @ Wg2 (+b_g2, pre-initialized). GEMM
// 4096x512x512; A staged from fp32 GEf with f16 cast, B from f16 Wg1t.
// Fused relu/dot epilogue; 16-lane shuffle reduce, atomicAdd per row.
// ---------------------------------------------------------------------------
__global__ __launch_bounds__(256) void gemm_graph(const float* __restrict__ GEf,
                                                  const _Float16* __restrict__ Bt,
                                                  const float* __restrict__ bg1,
                                                  const float* __restrict__ wg2,
                                                  float* __restrict__ gpred) {
    __shared__ _Float16 As[128][72];
    __shared__ _Float16 Bs[128][72];

    const int t   = threadIdx.x;
    const int bmb = blockIdx.x, bnb = blockIdx.y;
    const int w   = t >> 6, l = t & 63, quad = l >> 4, lr = l & 15;
    const int wm  = w & 1, wn = w >> 1;

    floatx4 acc[4][4];
    for (int mt = 0; mt < 4; ++mt)
        for (int nt = 0; nt < 4; ++nt)
            acc[mt][nt] = (floatx4){0.f, 0.f, 0.f, 0.f};

    const int arow0 = t >> 2;          // 0..63
    const int aseg  = (t & 3) * 16;

    for (int ko = 0; ko < 8; ++ko) {
        const int k0 = ko * 64;
        float4 av[2][4];
        for (int p = 0; p < 2; ++p) {
            int row = bmb * 128 + arow0 + p * 64;   // always < 4096
            const float4* src = (const float4*)(GEf + (size_t)row * HDIM + k0 + aseg);
            av[p][0] = src[0]; av[p][1] = src[1]; av[p][2] = src[2]; av[p][3] = src[3];
        }
        uint4 bvv[4];
        for (int it = 0; it < 4; ++it) {
            int idx = t + it * 256;            // < 1024
            int row = idx >> 3, c = (idx & 7) * 8;
            bvv[it] = *(const uint4*)(Bt + (size_t)(bnb * 128 + row) * HDIM + k0 + c);
        }
        __syncthreads();
        for (int p = 0; p < 2; ++p) {
            int row = arow0 + p * 64;
            half8 h0 = {(_Float16)av[p][0].x, (_Float16)av[p][0].y, (_Float16)av[p][0].z, (_Float16)av[p][0].w,
                        (_Float16)av[p][1].x, (_Float16)av[p][1].y, (_Float16)av[p][1].z, (_Float16)av[p][1].w};
            half8 h1 = {(_Float16)av[p][2].x, (_Float16)av[p][2].y, (_Float16)av[p][2].z, (_Float16)av[p][2].w,
                        (_Float16)av[p][3].x, (_Float16)av[p][3].y, (_Float16)av[p][3].z, (_Float16)av[p][3].w};
            *(half8*)&As[row][aseg]     = h0;
            *(half8*)&As[row][aseg + 8] = h1;
        }
        for (int it = 0; it < 4; ++it) {
            int idx = t + it * 256;
            int row = idx >> 3, c = (idx & 7) * 8;
            *(uint4*)&Bs[row][c] = bvv[it];
        }
        __syncthreads();
        for (int kk = 0; kk < 64; kk += 32) {
            half8 af[4], bf[4];
            for (int mt = 0; mt < 4; ++mt)
                af[mt] = *(const half8*)&As[wm * 64 + mt * 16 + lr][kk + quad * 8];
            for (int nt = 0; nt < 4; ++nt)
                bf[nt] = *(const half8*)&Bs[wn * 64 + nt * 16 + lr][kk + quad * 8];
            for (int mt = 0; mt < 4; ++mt)
                for (int nt = 0; nt < 4; ++nt)
                    acc[mt][nt] = __builtin_amdgcn_mfma_f32_16x16x32_f16(af[mt], bf[nt], acc[mt][nt], 0, 0, 0);
        }
    }

    float bg1v[4], wg2v[4];
    for (int nt = 0; nt < 4; ++nt) {
        int col = bnb * 128 + wn * 64 + nt * 16 + lr;
        bg1v[nt] = bg1[col];
        wg2v[nt] = wg2[col];
    }
    for (int mt = 0; mt < 4; ++mt) {
        for (int r = 0; r < 4; ++r) {
            int row = bmb * 128 + wm * 64 + mt * 16 + quad * 4 + r;
            float partial = 0.f;
            for (int nt = 0; nt < 4; ++nt) {
                float v = acc[mt][nt][r] + bg1v[nt];
                v = v > 0.f ? v : 0.f;
                partial += v * wg2v[nt];
            }
            partial += __shfl_xor(partial, 1);
            partial += __shfl_xor(partial, 2);
            partial += __shfl_xor(partial, 4);
            partial += __shfl_xor(partial, 8);
            if (lr == 0) atomicAdd(&gpred[row], partial);
        }
    }
}

// ---------------------------------------------------------------------------
extern "C" void kernel_launch(void* const* d_in, const int* in_sizes, int n_in,
                              void* d_out, int out_size, void* d_ws, size_t ws_size,
                              hipStream_t stream) {
    const float* A    = (const float*)d_in[0];
    const float* Wn   = (const float*)d_in[1];
    const float* bn   = (const float*)d_in[2];
    const float* We   = (const float*)d_in[3];
    const float* be   = (const float*)d_in[4];
    const float* Wg1  = (const float*)d_in[5];
    const float* bg1  = (const float*)d_in[6];
    const float* Wg2  = (const float*)d_in[7];
    const float* bg2  = (const float*)d_in[8];
    const int*   ei   = (const int*)d_in[9];
    const int*   batch= (const int*)d_in[11];

    char* ws = (char*)d_ws;
    float*    P    = (float*)(ws + WS_P);
    _Float16* Bmat = (_Float16*)(ws + WS_BMAT);
    float*    bias = (float*)(ws + WS_BIAS);
    float*    GEf  = (float*)(ws + WS_GEF);
    _Float16* Wg1t = (_Float16*)(ws + WS_WG1T);

    float* node_out = (float*)d_out;
    float* edge_out = node_out + NODE_OUT_SZ;
    float* gpred    = edge_out + EDGE_OUT_SZ;

    pack_kernel<<<dim3(1361), dim3(256), 0, stream>>>(Wn, bn, We, be, Wg1, bg2, Bmat, bias, Wg1t, gpred);
    zero_ge<<<dim3(NGRAPH * HDIM / 4 / 256), dim3(256), 0, stream>>>((float4*)GEf);
    gemm_node<<<dim3((NATOMS + 127) / 128), dim3(256), 0, stream>>>(A, Bmat, bias, batch, node_out, P, GEf);
    edge_kernel<<<dim3(NBOND / 16), dim3(256), 0, stream>>>(ei, P, edge_out);
    gemm_graph<<<dim3(32, 4), dim3(256), 0, stream>>>(GEf, Wg1t, bg1, Wg2, gpred);
}